// Round 11
// baseline (407.657 us; speedup 1.0000x reference)
//
#include <hip/hip_runtime.h>

#define NNODE 20000
#define NEDGE 320000
#define CH 256
#define NODES_PER_G 400
#define NG 50
#define JKW 768
#define RS_BN 0.99999500003749981f
#define LDSP 136
#define NBLK_SCAN 79

typedef unsigned short u16;
typedef unsigned int u32;
typedef __attribute__((ext_vector_type(8))) short short8;
typedef __attribute__((ext_vector_type(4))) float f32x4;

__device__ __forceinline__ float b2f(u16 h) {
    return __uint_as_float(((u32)h) << 16);
}
__device__ __forceinline__ u16 f2b(float f) {
    u32 x = __float_as_uint(f);
    u32 r = x + 0x7fffu + ((x >> 16) & 1u);
    return (u16)(r >> 16);
}
__device__ __forceinline__ float san(float v) {
    v = fminf(fmaxf(v, -1e30f), 1e30f);
    return (v == v) ? v : 0.0f;
}

// dtype detect: flag=0 bf16, flag=1 fp32
__global__ void k_detect(const u16* xw, int* flag) {
    int t = (int)threadIdx.x;
    int b = (int)blockIdx.x;
    if (t > 0 || b > 0) return;
    int cnt = 0;
    for (int i = 0; i < 256; ++i) {
        int v = (int)xw[i * 2];
        int e = (v >> 7) & 0xFF;
        if (e >= 0x60 && e <= 0x8F) ++cnt;
    }
    flag[0] = (cnt >= 192) ? 0 : 1;
}

// merged conversion for all small params -> pbuf layout
__global__ void k_cvt_all(const u16* g4b, const float* g4f,
                          const u16* g5b, const float* g5f,
                          const u16* g6b, const float* g6f,
                          const u16* g7b, const float* g7f,
                          const u16* g8b, const float* g8f,
                          const u16* g9b, const float* g9f,
                          const u16* gab, const float* gaf,
                          const u16* gbb, const float* gbf,
                          u16* pbuf, const int* flag) {
    int i = (int)(blockIdx.x * 256u + threadIdx.x);
    int dt = flag[0];
    const u16* sb = g4b;
    const float* sf = g4f;
    int si = -1;
    if (i < 768) { sb = g4b; sf = g4f; si = i; }
    else if (i < 1536) { sb = g5b; sf = g5f; si = i - 768; }
    else if (i < 1792) { sb = g7b; sf = g7f; si = i - 1536; }
    else if (i < 2048) { sb = g8b; sf = g8f; si = i - 1792; }
    else if (i < 2304) { sb = g9b; sf = g9f; si = i - 2048; }
    else if (i < 2816) { sb = gab; sf = gaf; si = i - 2304; }
    else if (i < 2818) { sb = gbb; sf = gbf; si = i - 2816; }
    else if (i >= 3072 && i < 199680) { sb = g6b; sf = g6f; si = i - 3072; }
    if (si < 0) return;
    u16 v;
    if (dt != 0) {
        v = f2b(sf[si]);
    } else {
        v = sb[si];
    }
    int vi = (int)v;
    if ((vi & 0x7F80) == 0x7F80) v = (u16)0;
    pbuf[i] = v;
}

__global__ void k_zero(int* deg) {
    int i = (int)(blockIdx.x * 256u + threadIdx.x);
    if (i < NNODE) deg[i] = 0;
}

__global__ void k_zeroz(float* zagg) {
    int i = (int)(blockIdx.x * 256u + threadIdx.x);
    if (i < NG * JKW) zagg[i] = 0.0f;
}

__global__ void k_deg(const int* ei, int* deg) {
    int e = (int)(blockIdx.x * 256u + threadIdx.x);
    if (e < NEDGE) {
        int r = ei[e];
        if (r >= 0 && r < NNODE) atomicAdd(&deg[r], 1);
    }
}

// 3-phase parallel scan: per-block sums
__global__ __launch_bounds__(256) void k_bsum(const int* deg, int* bsum) {
    __shared__ int sd[256];
    int b = (int)blockIdx.x;
    int t = (int)threadIdx.x;
    int i = b * 256 + t;
    sd[t] = (i < NNODE) ? deg[i] : 0;
    __syncthreads();
    for (int s = 128; s > 0; s >>= 1) {
        if (t < s) sd[t] += sd[t + s];
        __syncthreads();
    }
    if (t == 0) bsum[b] = sd[0];
}

// exclusive scan of block sums (NBLK_SCAN <= 128); writes offs[NNODE]=total
__global__ __launch_bounds__(128) void k_bscan(const int* bsum, int* boff,
                                               int* offs) {
    __shared__ int ps[128];
    int t = (int)threadIdx.x;
    int v = (t < NBLK_SCAN) ? bsum[t] : 0;
    ps[t] = v;
    __syncthreads();
    for (int off = 1; off < 128; off <<= 1) {
        int u = (t >= off) ? ps[t - off] : 0;
        __syncthreads();
        ps[t] += u;
        __syncthreads();
    }
    if (t < NBLK_SCAN) boff[t] = ps[t] - v;
    if (t == 127) offs[NNODE] = ps[127];
}

// intra-block exclusive scan + block offset; fused offs/cursor/dis write
__global__ __launch_bounds__(256) void k_scat(const int* deg, const int* boff,
                                              int* offs, int* cursor,
                                              float* dis) {
    __shared__ int ps[256];
    int b = (int)blockIdx.x;
    int t = (int)threadIdx.x;
    int i = b * 256 + t;
    int d = (i < NNODE) ? deg[i] : 0;
    ps[t] = d;
    __syncthreads();
    for (int off = 1; off < 256; off <<= 1) {
        int u = (t >= off) ? ps[t - off] : 0;
        __syncthreads();
        ps[t] += u;
        __syncthreads();
    }
    if (i < NNODE) {
        int excl = ps[t] - d + boff[b];
        offs[i] = excl;
        cursor[i] = excl;
        dis[i] = (d > 0) ? san(rsqrtf((float)d)) : 0.0f;
    }
}

__global__ void k_fill(const int* ei, int* cursor, int* ccol) {
    int e = (int)(blockIdx.x * 256u + threadIdx.x);
    if (e < NEDGE) {
        int r = ei[e];
        int c = ei[NEDGE + e];
        if (r < 0 || r >= NNODE || c < 0 || c >= NNODE) return;
        int pos = atomicAdd(&cursor[r], 1);
        if (pos < 0 || pos >= NEDGE) return;
        ccol[pos] = c;
    }
}

// per-layer weight transpose: Wtl[j][k] = (k<256 ? W0[k][j] : W1[k-256][j])
__global__ void k_wt(const u16* wb, const float* wf, u16* Wtl, int l,
                     const int* flag) {
    int j = (int)blockIdx.x;
    int t = (int)threadIdx.x;
    int dt = flag[0];
    for (int i = 0; i < 2; ++i) {
        size_t si = ((size_t)(l * 2 + i) * 256 + (size_t)t) * 256 + (size_t)j;
        u16 v;
        if (dt != 0) {
            v = f2b(wf[si]);
        } else {
            v = wb[si];
        }
        int vi = (int)v;
        if ((vi & 0x7F80) == 0x7F80) v = (u16)0;
        Wtl[(size_t)j * 512 + (size_t)(i * 256 + t)] = v;
    }
}

// P = L_hat @ src: channel-slice-4 (L2 residency: 2.56MB/slice < 4MB/XCD L2)
// + 4-way edge unroll (MLP). Wave = 2 nodes x 32 lanes x ushort2.
// slice = blockIdx&3 -> round-robin XCD spread keeps slices XCD-local.
__global__ __launch_bounds__(256) void k_propP(const u16* srcb, const float* srcf,
                                               const int* offs, const int* ccol,
                                               const float* dis, u16* P,
                                               const int* flag, int use_f32) {
    int bid = (int)blockIdx.x;
    int slice = bid & 3;
    int nblk = bid >> 2;
    int tid = (int)threadIdx.x;
    int wv = tid >> 6;
    int lane = tid & 63;
    int half = lane >> 5;
    int cl = lane & 31;
    int node = nblk * 8 + wv * 2 + half;
    if (node >= NNODE) return;
    int cb = slice * 64 + cl * 2;
    float dis_i = dis[node];
    int e0 = offs[node];
    int e1 = offs[node + 1];
    if (e0 < 0) e0 = 0;
    if (e1 > NEDGE) e1 = NEDGE;
    int dt = (use_f32 != 0) ? flag[0] : 0;
    float a0 = 0.f, a1 = 0.f;
    float d0 = 0.f, d1 = 0.f;
    if (dt != 0) {
        int e = e0;
        for (; e + 3 < e1; e += 4) {
            int n0 = ccol[e];
            int n1 = ccol[e + 1];
            int n2 = ccol[e + 2];
            int n3 = ccol[e + 3];
            int k0 = (n0 >= 0 && n0 < NNODE) ? 1 : 0;
            int k1 = (n1 >= 0 && n1 < NNODE) ? 1 : 0;
            int k2 = (n2 >= 0 && n2 < NNODE) ? 1 : 0;
            int k3 = (n3 >= 0 && n3 < NNODE) ? 1 : 0;
            n0 = (k0 != 0) ? n0 : 0;
            n1 = (k1 != 0) ? n1 : 0;
            n2 = (k2 != 0) ? n2 : 0;
            n3 = (k3 != 0) ? n3 : 0;
            float w0 = (k0 != 0) ? (-dis_i * dis[n0]) : 0.f;
            float w1 = (k1 != 0) ? (-dis_i * dis[n1]) : 0.f;
            float w2 = (k2 != 0) ? (-dis_i * dis[n2]) : 0.f;
            float w3 = (k3 != 0) ? (-dis_i * dis[n3]) : 0.f;
            float2 v0 = *(const float2*)(srcf + (size_t)n0 * CH + (size_t)cb);
            float2 v1 = *(const float2*)(srcf + (size_t)n1 * CH + (size_t)cb);
            float2 v2 = *(const float2*)(srcf + (size_t)n2 * CH + (size_t)cb);
            float2 v3 = *(const float2*)(srcf + (size_t)n3 * CH + (size_t)cb);
            a0 += w0 * v0.x; a1 += w0 * v0.y;
            d0 += w1 * v1.x; d1 += w1 * v1.y;
            a0 += w2 * v2.x; a1 += w2 * v2.y;
            d0 += w3 * v3.x; d1 += w3 * v3.y;
        }
        for (; e < e1; ++e) {
            int nb = ccol[e];
            if (nb < 0 || nb >= NNODE) continue;
            float wvt = -dis_i * dis[nb];
            float2 v = *(const float2*)(srcf + (size_t)nb * CH + (size_t)cb);
            a0 += wvt * v.x; a1 += wvt * v.y;
        }
    } else {
        int e = e0;
        for (; e + 3 < e1; e += 4) {
            int n0 = ccol[e];
            int n1 = ccol[e + 1];
            int n2 = ccol[e + 2];
            int n3 = ccol[e + 3];
            int k0 = (n0 >= 0 && n0 < NNODE) ? 1 : 0;
            int k1 = (n1 >= 0 && n1 < NNODE) ? 1 : 0;
            int k2 = (n2 >= 0 && n2 < NNODE) ? 1 : 0;
            int k3 = (n3 >= 0 && n3 < NNODE) ? 1 : 0;
            n0 = (k0 != 0) ? n0 : 0;
            n1 = (k1 != 0) ? n1 : 0;
            n2 = (k2 != 0) ? n2 : 0;
            n3 = (k3 != 0) ? n3 : 0;
            float w0 = (k0 != 0) ? (-dis_i * dis[n0]) : 0.f;
            float w1 = (k1 != 0) ? (-dis_i * dis[n1]) : 0.f;
            float w2 = (k2 != 0) ? (-dis_i * dis[n2]) : 0.f;
            float w3 = (k3 != 0) ? (-dis_i * dis[n3]) : 0.f;
            ushort2 v0 = *(const ushort2*)(srcb + (size_t)n0 * CH + (size_t)cb);
            ushort2 v1 = *(const ushort2*)(srcb + (size_t)n1 * CH + (size_t)cb);
            ushort2 v2 = *(const ushort2*)(srcb + (size_t)n2 * CH + (size_t)cb);
            ushort2 v3 = *(const ushort2*)(srcb + (size_t)n3 * CH + (size_t)cb);
            a0 += w0 * b2f(v0.x); a1 += w0 * b2f(v0.y);
            d0 += w1 * b2f(v1.x); d1 += w1 * b2f(v1.y);
            a0 += w2 * b2f(v2.x); a1 += w2 * b2f(v2.y);
            d0 += w3 * b2f(v3.x); d1 += w3 * b2f(v3.y);
        }
        for (; e < e1; ++e) {
            int nb = ccol[e];
            if (nb < 0 || nb >= NNODE) continue;
            float wvt = -dis_i * dis[nb];
            ushort2 v = *(const ushort2*)(srcb + (size_t)nb * CH + (size_t)cb);
            a0 += wvt * b2f(v.x); a1 += wvt * b2f(v.y);
        }
    }
    ushort2 o;
    o.x = f2b(san(a0 + d0));
    o.y = f2b(san(a1 + d1));
    *(ushort2*)(P + (size_t)node * CH + (size_t)cb) = o;
}

// fast GEMM (no aliasing): grid (rows/64, 4); block = 64 rows x 64 cols, K=512
__global__ __launch_bounds__(256) void k_gemm4(const u16* srcb, const float* srcf,
                                               const u16* P, const u16* Wtl,
                                               const u16* gam, const u16* bet,
                                               u16* dst, int mode,
                                               const int* flag, int use_f32) {
    __shared__ u16 As[64 * LDSP];
    __shared__ u16 Bs[64 * LDSP];
    const int tid = (int)threadIdx.x;
    const int m0 = (int)blockIdx.x * 64;
    const int j0 = (int)blockIdx.y * 64;
    const int w = tid >> 6;
    const int lane = tid & 63;
    const int mL = lane & 15;
    const int q = lane >> 4;
    const int dt = (use_f32 != 0) ? flag[0] : 0;
    f32x4 z4 = {0.f, 0.f, 0.f, 0.f};
    f32x4 acc[4] = {z4, z4, z4, z4};

    for (int kh = 0; kh < 4; ++kh) {
        __syncthreads();
#pragma unroll
        for (int it = 0; it < 4; ++it) {
            int idx = it * 256 + tid;
            int r = idx >> 4;
            int c8 = idx & 15;
            int gm = m0 + r;
            uint4 av = make_uint4(0u, 0u, 0u, 0u);
            if (gm < NNODE) {
                if (kh < 2) {
                    size_t off = (size_t)gm * CH + (size_t)(kh * 128 + c8 * 8);
                    if (dt != 0) {
                        const float4* fp = (const float4*)(srcf + off);
                        float4 v0 = fp[0];
                        float4 v1 = fp[1];
                        av.x = (u32)f2b(v0.x) | ((u32)f2b(v0.y) << 16);
                        av.y = (u32)f2b(v0.z) | ((u32)f2b(v0.w) << 16);
                        av.z = (u32)f2b(v1.x) | ((u32)f2b(v1.y) << 16);
                        av.w = (u32)f2b(v1.z) | ((u32)f2b(v1.w) << 16);
                    } else {
                        av = *(const uint4*)(srcb + off);
                    }
                } else {
                    av = *(const uint4*)(P + (size_t)gm * CH +
                                         (size_t)((kh - 2) * 128 + c8 * 8));
                }
            }
            *(uint4*)(&As[r * LDSP + c8 * 8]) = av;
            uint4 bv = *(const uint4*)(Wtl + (size_t)(j0 + r) * 512 +
                                       (size_t)(kh * 128 + c8 * 8));
            *(uint4*)(&Bs[r * LDSP + c8 * 8]) = bv;
        }
        __syncthreads();
#pragma unroll
        for (int kt = 0; kt < 4; ++kt) {
            int ko = kt * 32 + q * 8;
            short8 a = *(const short8*)(&As[(w * 16 + mL) * LDSP + ko]);
#pragma unroll
            for (int t = 0; t < 4; ++t) {
                short8 b = *(const short8*)(&Bs[(t * 16 + mL) * LDSP + ko]);
                acc[t] = __builtin_amdgcn_mfma_f32_16x16x32_bf16(a, b, acc[t],
                                                                 0, 0, 0);
            }
        }
    }
#pragma unroll
    for (int t = 0; t < 4; ++t) {
        int j = j0 + t * 16 + mL;
        float s = b2f(gam[j]) * RS_BN;
        float bb = b2f(bet[j]);
#pragma unroll
        for (int rr = 0; rr < 4; ++rr) {
            int gm = m0 + w * 16 + q * 4 + rr;
            if (gm < NNODE) {
                float v = acc[t][rr];
                v = (mode == 0) ? fmaxf(v * s + bb, 0.f)
                                : fmaxf(v, 0.f) * s + bb;
                dst[(size_t)gm * CH + (size_t)j] = f2b(san(v));
            }
        }
    }
}

// aliased fallback GEMM (block owns full rows; dst may alias src/P)
__global__ __launch_bounds__(256) void k_gemma(const u16* srcb, const float* srcf,
                                               const u16* P, const u16* Wtl,
                                               const u16* gam, const u16* bet,
                                               u16* dst, int mode,
                                               const int* flag, int use_f32) {
    __shared__ u16 As[64 * LDSP];
    __shared__ u16 Bs[64 * LDSP];
    const int tid = (int)threadIdx.x;
    const int m0 = (int)blockIdx.x * 64;
    const int w = tid >> 6;
    const int lane = tid & 63;
    const int mL = lane & 15;
    const int q = lane >> 4;
    const int dt = (use_f32 != 0) ? flag[0] : 0;
    f32x4 z4 = {0.f, 0.f, 0.f, 0.f};
    f32x4 acc[4][4];
#pragma unroll
    for (int jt = 0; jt < 4; ++jt)
#pragma unroll
        for (int t = 0; t < 4; ++t) acc[jt][t] = z4;

    for (int kh = 0; kh < 4; ++kh) {
        __syncthreads();
#pragma unroll
        for (int it = 0; it < 4; ++it) {
            int idx = it * 256 + tid;
            int r = idx >> 4;
            int c8 = idx & 15;
            int gm = m0 + r;
            uint4 av = make_uint4(0u, 0u, 0u, 0u);
            if (gm < NNODE) {
                if (kh < 2) {
                    size_t off = (size_t)gm * CH + (size_t)(kh * 128 + c8 * 8);
                    if (dt != 0) {
                        const float4* fp = (const float4*)(srcf + off);
                        float4 v0 = fp[0];
                        float4 v1 = fp[1];
                        av.x = (u32)f2b(v0.x) | ((u32)f2b(v0.y) << 16);
                        av.y = (u32)f2b(v0.z) | ((u32)f2b(v0.w) << 16);
                        av.z = (u32)f2b(v1.x) | ((u32)f2b(v1.y) << 16);
                        av.w = (u32)f2b(v1.z) | ((u32)f2b(v1.w) << 16);
                    } else {
                        av = *(const uint4*)(srcb + off);
                    }
                } else {
                    av = *(const uint4*)(P + (size_t)gm * CH +
                                         (size_t)((kh - 2) * 128 + c8 * 8));
                }
            }
            *(uint4*)(&As[r * LDSP + c8 * 8]) = av;
        }
        for (int jt = 0; jt < 4; ++jt) {
            if (jt > 0) __syncthreads();
#pragma unroll
            for (int it = 0; it < 4; ++it) {
                int idx = it * 256 + tid;
                int r = idx >> 4;
                int c8 = idx & 15;
                uint4 bv = *(const uint4*)(Wtl + (size_t)(jt * 64 + r) * 512 +
                                           (size_t)(kh * 128 + c8 * 8));
                *(uint4*)(&Bs[r * LDSP + c8 * 8]) = bv;
            }
            __syncthreads();
#pragma unroll
            for (int kt = 0; kt < 4; ++kt) {
                int ko = kt * 32 + q * 8;
                short8 a = *(const short8*)(&As[(w * 16 + mL) * LDSP + ko]);
#pragma unroll
                for (int t = 0; t < 4; ++t) {
                    short8 b = *(const short8*)(&Bs[(t * 16 + mL) * LDSP + ko]);
                    acc[jt][t] = __builtin_amdgcn_mfma_f32_16x16x32_bf16(
                        a, b, acc[jt][t], 0, 0, 0);
                }
            }
        }
    }
#pragma unroll
    for (int jt = 0; jt < 4; ++jt) {
#pragma unroll
        for (int t = 0; t < 4; ++t) {
            int j = jt * 64 + t * 16 + mL;
            float s = b2f(gam[j]) * RS_BN;
            float bb = b2f(bet[j]);
#pragma unroll
            for (int rr = 0; rr < 4; ++rr) {
                int gm = m0 + w * 16 + q * 4 + rr;
                if (gm < NNODE) {
                    float v = acc[jt][t][rr];
                    v = (mode == 0) ? fmaxf(v * s + bb, 0.f)
                                    : fmaxf(v, 0.f) * s + bb;
                    dst[(size_t)gm * CH + (size_t)j] = f2b(san(v));
                }
            }
        }
    }
}

// pool: 8 chunks/graph, atomic accumulate into zagg (zeroed per launch)
__global__ __launch_bounds__(256) void k_pool(const u16* h, float* zagg, int l) {
    int b = (int)blockIdx.x;
    int g = b >> 3;
    int chk = b & 7;
    int c = (int)threadIdx.x;
    const u16* p = h + ((size_t)g * NODES_PER_G + (size_t)(chk * 50)) * CH +
                   (size_t)c;
    float s = 0.f;
#pragma unroll 5
    for (int n = 0; n < 50; ++n) s += b2f(p[(size_t)n * CH]);
    atomicAdd(&zagg[g * JKW + l * CH + c], s * (1.0f / (float)NODES_PER_G));
}

// write z_agg output region from zagg
__global__ __launch_bounds__(256) void k_zout(const float* zagg, u16* outb,
                                              float* outf, const int* flag) {
    int i = (int)(blockIdx.x * 256u + threadIdx.x);
    if (i >= NG * JKW) return;
    float v = san(zagg[i]);
    if (flag[0] != 0) {
        outf[i] = v;
    } else {
        outb[i] = f2b(v);
    }
}

__global__ __launch_bounds__(256) void k_head(const float* zagg, const u16* w1,
                                              const u16* b1, const u16* cg,
                                              const u16* cbe, const u16* w2,
                                              const u16* b2, u16* loutb,
                                              float* loutf, const int* flag) {
    __shared__ float zin[JKW];
    __shared__ float zz[256];
    __shared__ float red[256];
    int g = (int)blockIdx.x;
    int t = (int)threadIdx.x;
    for (int i = t; i < JKW; i += 256) zin[i] = zagg[g * JKW + i];
    __syncthreads();
    float acc = b2f(b1[t]);
    const u16* wr = w1 + (size_t)t * JKW;
    for (int k = 0; k < JKW; ++k) acc += zin[k] * b2f(wr[k]);
    float z = san(fmaxf(acc, 0.f) * (b2f(cg[t]) * RS_BN) + b2f(cbe[t]));
    zz[t] = z;
    __syncthreads();
    for (int cls = 0; cls < 2; ++cls) {
        red[t] = zz[t] * b2f(w2[cls * 256 + t]);
        __syncthreads();
        for (int s = 128; s > 0; s >>= 1) {
            if (t < s) red[t] += red[t + s];
            __syncthreads();
        }
        if (t == 0) {
            float val = san(red[0] + b2f(b2[cls]));
            if (flag[0] != 0) {
                loutf[g * 2 + cls] = val;
            } else {
                loutb[g * 2 + cls] = f2b(val);
            }
        }
        __syncthreads();
    }
}

extern "C" void kernel_launch(void* const* d_in, const int* in_sizes, int n_in,
                              void* d_out, int out_size, void* d_ws, size_t ws_size,
                              hipStream_t stream) {
    (void)in_sizes; (void)n_in; (void)out_size;
    const u16*   xb  = (const u16*)d_in[0];
    const float* xf  = (const float*)d_in[0];
    u16*         xs  = (u16*)d_in[0];   // scratch h-buffer; harness restores d_in
    const int*   ei  = (const int*)d_in[1];
    const u16*   cwb = (const u16*)d_in[3];
    const float* cwf = (const float*)d_in[3];
    u16*   outb = (u16*)d_out;
    float* outf = (float*)d_out;

    char* p = (char*)d_ws;
    size_t used = 0;
    auto alloc = [&](size_t bytes) {
        char* r = p;
        size_t a = (bytes + 255) & ~(size_t)255;
        p += a;
        used += a;
        return r;
    };
    int*   deg    = (int*)alloc((size_t)NNODE * 4);
    int*   offs   = (int*)alloc((size_t)(NNODE + 1) * 4);
    int*   cursor = (int*)alloc((size_t)NNODE * 4);
    float* dis    = (float*)alloc((size_t)NNODE * 4);
    int*   ccol   = (int*)alloc((size_t)NEDGE * 4);
    int*   bsum   = (int*)alloc((size_t)NBLK_SCAN * 4);
    int*   boff   = (int*)alloc((size_t)NBLK_SCAN * 4);
    u16*   Wtl    = (u16*)alloc((size_t)256 * 512 * 2);
    u16*   P0     = (u16*)alloc((size_t)NNODE * CH * 2);
    float* zagg   = (float*)alloc((size_t)NG * JKW * 4);
    int*   flag   = (int*)alloc(256);
    u16*   pbuf   = (u16*)alloc((size_t)199680 * 2);
    u16*   hA     = (u16*)alloc((size_t)NNODE * CH * 2);  // fast path only
    int fast = (used <= ws_size) ? 1 : 0;

    u16* c_bng = pbuf + 0;
    u16* c_bnb = pbuf + 768;
    u16* c_b1  = pbuf + 1536;
    u16* c_cg  = pbuf + 1792;
    u16* c_cbe = pbuf + 2048;
    u16* c_w2  = pbuf + 2304;
    u16* c_b2  = pbuf + 2816;
    u16* c_w1  = pbuf + 3072;

    k_detect<<<1, 64, 0, stream>>>(xb, flag);
    k_cvt_all<<<780, 256, 0, stream>>>(
        (const u16*)d_in[4], (const float*)d_in[4],
        (const u16*)d_in[5], (const float*)d_in[5],
        (const u16*)d_in[6], (const float*)d_in[6],
        (const u16*)d_in[7], (const float*)d_in[7],
        (const u16*)d_in[8], (const float*)d_in[8],
        (const u16*)d_in[9], (const float*)d_in[9],
        (const u16*)d_in[10], (const float*)d_in[10],
        (const u16*)d_in[11], (const float*)d_in[11],
        pbuf, flag);

    k_zero<<<(NNODE + 255) / 256, 256, 0, stream>>>(deg);
    k_zeroz<<<(NG * JKW + 255) / 256, 256, 0, stream>>>(zagg);
    k_deg<<<(NEDGE + 255) / 256, 256, 0, stream>>>(ei, deg);
    k_bsum<<<NBLK_SCAN, 256, 0, stream>>>(deg, bsum);
    k_bscan<<<1, 128, 0, stream>>>(bsum, boff, offs);
    k_scat<<<NBLK_SCAN, 256, 0, stream>>>(deg, boff, offs, cursor, dis);
    k_fill<<<(NEDGE + 255) / 256, 256, 0, stream>>>(ei, cursor, ccol);

    const int gblk = (NNODE + 63) / 64;
    const int pblk = (NNODE / 8) * 4;  // 8 nodes/block x 4 channel slices
    dim3 g4(gblk, 4, 1);
    for (int l = 0; l < 3; ++l) {
        int uf = (l == 0) ? 1 : 0;
        int mode = (l == 0) ? 0 : 1;
        k_wt<<<256, 256, 0, stream>>>(cwb, cwf, Wtl, l, flag);
        if (fast != 0) {
            const u16* sb;
            u16* hd;
            if (l == 0)      { sb = xb; hd = hA; }
            else if (l == 1) { sb = hA; hd = xs; }
            else             { sb = xs; hd = hA; }
            k_propP<<<pblk, 256, 0, stream>>>(sb, xf, offs, ccol, dis, P0,
                                              flag, uf);
            k_gemm4<<<g4, 256, 0, stream>>>(sb, xf, P0, Wtl, c_bng + l * 256,
                                            c_bnb + l * 256, hd, mode, flag, uf);
            k_pool<<<NG * 8, 256, 0, stream>>>(hd, zagg, l);
        } else {
            const u16* sb;
            u16* hp;
            if (l == 0)      { sb = xb; hp = P0; }
            else if (l == 1) { sb = P0; hp = xs; }
            else             { sb = xs; hp = P0; }
            k_propP<<<pblk, 256, 0, stream>>>(sb, xf, offs, ccol, dis, hp,
                                              flag, uf);
            k_gemma<<<gblk, 256, 0, stream>>>(sb, xf, hp, Wtl, c_bng + l * 256,
                                              c_bnb + l * 256, hp, mode, flag, uf);
            k_pool<<<NG * 8, 256, 0, stream>>>(hp, zagg, l);
        }
    }
    k_zout<<<(NG * JKW + 255) / 256, 256, 0, stream>>>(zagg, outb, outf, flag);
    k_head<<<NG, 256, 0, stream>>>(zagg, c_w1, c_b1, c_cg, c_cbe, c_w2, c_b2,
                                   outb + NG * JKW, outf + NG * JKW, flag);
}

// Round 12
// 352.435 us; speedup vs baseline: 1.1567x; 1.1567x over previous
//
#include <hip/hip_runtime.h>

#define NNODE 20000
#define NEDGE 320000
#define CH 256
#define NODES_PER_G 400
#define NG 50
#define JKW 768
#define RS_BN 0.99999500003749981f
#define LDSP 136
#define NBLK_SCAN 79

typedef unsigned short u16;
typedef unsigned int u32;
typedef __attribute__((ext_vector_type(8))) short short8;
typedef __attribute__((ext_vector_type(4))) float f32x4;

__device__ __forceinline__ float b2f(u16 h) {
    return __uint_as_float(((u32)h) << 16);
}
__device__ __forceinline__ u16 f2b(float f) {
    u32 x = __float_as_uint(f);
    u32 r = x + 0x7fffu + ((x >> 16) & 1u);
    return (u16)(r >> 16);
}
__device__ __forceinline__ float san(float v) {
    v = fminf(fmaxf(v, -1e30f), 1e30f);
    return (v == v) ? v : 0.0f;
}

// dtype detect: flag=0 bf16, flag=1 fp32
__global__ void k_detect(const u16* xw, int* flag) {
    int t = (int)threadIdx.x;
    int b = (int)blockIdx.x;
    if (t > 0 || b > 0) return;
    int cnt = 0;
    for (int i = 0; i < 256; ++i) {
        int v = (int)xw[i * 2];
        int e = (v >> 7) & 0xFF;
        if (e >= 0x60 && e <= 0x8F) ++cnt;
    }
    flag[0] = (cnt >= 192) ? 0 : 1;
}

// merged conversion for all small params -> pbuf layout
__global__ void k_cvt_all(const u16* g4b, const float* g4f,
                          const u16* g5b, const float* g5f,
                          const u16* g6b, const float* g6f,
                          const u16* g7b, const float* g7f,
                          const u16* g8b, const float* g8f,
                          const u16* g9b, const float* g9f,
                          const u16* gab, const float* gaf,
                          const u16* gbb, const float* gbf,
                          u16* pbuf, const int* flag) {
    int i = (int)(blockIdx.x * 256u + threadIdx.x);
    int dt = flag[0];
    const u16* sb = g4b;
    const float* sf = g4f;
    int si = -1;
    if (i < 768) { sb = g4b; sf = g4f; si = i; }
    else if (i < 1536) { sb = g5b; sf = g5f; si = i - 768; }
    else if (i < 1792) { sb = g7b; sf = g7f; si = i - 1536; }
    else if (i < 2048) { sb = g8b; sf = g8f; si = i - 1792; }
    else if (i < 2304) { sb = g9b; sf = g9f; si = i - 2048; }
    else if (i < 2816) { sb = gab; sf = gaf; si = i - 2304; }
    else if (i < 2818) { sb = gbb; sf = gbf; si = i - 2816; }
    else if (i >= 3072 && i < 199680) { sb = g6b; sf = g6f; si = i - 3072; }
    if (si < 0) return;
    u16 v;
    if (dt != 0) {
        v = f2b(sf[si]);
    } else {
        v = sb[si];
    }
    int vi = (int)v;
    if ((vi & 0x7F80) == 0x7F80) v = (u16)0;
    pbuf[i] = v;
}

__global__ void k_zero(int* deg) {
    int i = (int)(blockIdx.x * 256u + threadIdx.x);
    if (i < NNODE) deg[i] = 0;
}

__global__ void k_zeroz(float* zagg) {
    int i = (int)(blockIdx.x * 256u + threadIdx.x);
    if (i < NG * JKW) zagg[i] = 0.0f;
}

__global__ void k_deg(const int* ei, int* deg) {
    int e = (int)(blockIdx.x * 256u + threadIdx.x);
    if (e < NEDGE) {
        int r = ei[e];
        if (r >= 0 && r < NNODE) atomicAdd(&deg[r], 1);
    }
}

// 3-phase parallel scan: per-block sums
__global__ __launch_bounds__(256) void k_bsum(const int* deg, int* bsum) {
    __shared__ int sd[256];
    int b = (int)blockIdx.x;
    int t = (int)threadIdx.x;
    int i = b * 256 + t;
    sd[t] = (i < NNODE) ? deg[i] : 0;
    __syncthreads();
    for (int s = 128; s > 0; s >>= 1) {
        if (t < s) sd[t] += sd[t + s];
        __syncthreads();
    }
    if (t == 0) bsum[b] = sd[0];
}

// exclusive scan of block sums (NBLK_SCAN <= 128); writes offs[NNODE]=total
__global__ __launch_bounds__(128) void k_bscan(const int* bsum, int* boff,
                                               int* offs) {
    __shared__ int ps[128];
    int t = (int)threadIdx.x;
    int v = (t < NBLK_SCAN) ? bsum[t] : 0;
    ps[t] = v;
    __syncthreads();
    for (int off = 1; off < 128; off <<= 1) {
        int u = (t >= off) ? ps[t - off] : 0;
        __syncthreads();
        ps[t] += u;
        __syncthreads();
    }
    if (t < NBLK_SCAN) boff[t] = ps[t] - v;
    if (t == 127) offs[NNODE] = ps[127];
}

// intra-block exclusive scan + block offset; fused offs/cursor/dis write
__global__ __launch_bounds__(256) void k_scat(const int* deg, const int* boff,
                                              int* offs, int* cursor,
                                              float* dis) {
    __shared__ int ps[256];
    int b = (int)blockIdx.x;
    int t = (int)threadIdx.x;
    int i = b * 256 + t;
    int d = (i < NNODE) ? deg[i] : 0;
    ps[t] = d;
    __syncthreads();
    for (int off = 1; off < 256; off <<= 1) {
        int u = (t >= off) ? ps[t - off] : 0;
        __syncthreads();
        ps[t] += u;
        __syncthreads();
    }
    if (i < NNODE) {
        int excl = ps[t] - d + boff[b];
        offs[i] = excl;
        cursor[i] = excl;
        dis[i] = (d > 0) ? san(rsqrtf((float)d)) : 0.0f;
    }
}

// CSR fill + per-edge norm weight (removes dependent dis load from propP)
__global__ void k_fill(const int* ei, const float* dis, int* cursor, int* ccol,
                       float* cnorm) {
    int e = (int)(blockIdx.x * 256u + threadIdx.x);
    if (e < NEDGE) {
        int r = ei[e];
        int c = ei[NEDGE + e];
        if (r < 0 || r >= NNODE || c < 0 || c >= NNODE) return;
        int pos = atomicAdd(&cursor[r], 1);
        if (pos < 0 || pos >= NEDGE) return;
        ccol[pos] = c;
        cnorm[pos] = san(-(dis[r] * dis[c]));
    }
}

// per-layer weight transpose: Wtl[j][k] = (k<256 ? W0[k][j] : W1[k-256][j])
__global__ void k_wt(const u16* wb, const float* wf, u16* Wtl, int l,
                     const int* flag) {
    int j = (int)blockIdx.x;
    int t = (int)threadIdx.x;
    int dt = flag[0];
    for (int i = 0; i < 2; ++i) {
        size_t si = ((size_t)(l * 2 + i) * 256 + (size_t)t) * 256 + (size_t)j;
        u16 v;
        if (dt != 0) {
            v = f2b(wf[si]);
        } else {
            v = wb[si];
        }
        int vi = (int)v;
        if ((vi & 0x7F80) == 0x7F80) v = (u16)0;
        Wtl[(size_t)j * 512 + (size_t)(i * 256 + t)] = v;
    }
}

// P = L_hat @ src: wave per node, ushort4/lane (full 512B row per wave-load),
// 8-way edge unroll + streamed cnorm (short dependent chain: ccol -> row)
__global__ __launch_bounds__(256) void k_propP(const u16* srcb, const float* srcf,
                                               const int* offs, const int* ccol,
                                               const float* cnorm, u16* P,
                                               const int* flag, int use_f32) {
    int wid = (int)(blockIdx.x * 4u + (threadIdx.x >> 6));
    if (wid >= NNODE) return;
    int lane = (int)(threadIdx.x & 63u);
    int c0 = lane * 4;
    int e0 = offs[wid];
    int e1 = offs[wid + 1];
    if (e0 < 0) e0 = 0;
    if (e1 > NEDGE) e1 = NEDGE;
    int dt = (use_f32 != 0) ? flag[0] : 0;
    float a0 = 0.f, a1 = 0.f, a2 = 0.f, a3 = 0.f;
    float d0 = 0.f, d1 = 0.f, d2 = 0.f, d3 = 0.f;
    if (dt != 0) {
        int e = e0;
        for (; e + 3 < e1; e += 4) {
            int n[4];
            float w[4];
#pragma unroll
            for (int u = 0; u < 4; ++u) {
                int nb = ccol[e + u];
                int ok = (nb >= 0 && nb < NNODE) ? 1 : 0;
                n[u] = (ok != 0) ? nb : 0;
                w[u] = (ok != 0) ? cnorm[e + u] : 0.f;
            }
            float4 v0 = *(const float4*)(srcf + (size_t)n[0] * CH + (size_t)c0);
            float4 v1 = *(const float4*)(srcf + (size_t)n[1] * CH + (size_t)c0);
            float4 v2 = *(const float4*)(srcf + (size_t)n[2] * CH + (size_t)c0);
            float4 v3 = *(const float4*)(srcf + (size_t)n[3] * CH + (size_t)c0);
            a0 += w[0] * v0.x; a1 += w[0] * v0.y; a2 += w[0] * v0.z; a3 += w[0] * v0.w;
            d0 += w[1] * v1.x; d1 += w[1] * v1.y; d2 += w[1] * v1.z; d3 += w[1] * v1.w;
            a0 += w[2] * v2.x; a1 += w[2] * v2.y; a2 += w[2] * v2.z; a3 += w[2] * v2.w;
            d0 += w[3] * v3.x; d1 += w[3] * v3.y; d2 += w[3] * v3.z; d3 += w[3] * v3.w;
        }
        for (; e < e1; ++e) {
            int nb = ccol[e];
            if (nb < 0 || nb >= NNODE) continue;
            float wv = cnorm[e];
            float4 v = *(const float4*)(srcf + (size_t)nb * CH + (size_t)c0);
            a0 += wv * v.x; a1 += wv * v.y; a2 += wv * v.z; a3 += wv * v.w;
        }
    } else {
        int e = e0;
        for (; e + 7 < e1; e += 8) {
            int n[8];
            float w[8];
#pragma unroll
            for (int u = 0; u < 8; ++u) {
                int nb = ccol[e + u];
                int ok = (nb >= 0 && nb < NNODE) ? 1 : 0;
                n[u] = (ok != 0) ? nb : 0;
                w[u] = (ok != 0) ? cnorm[e + u] : 0.f;
            }
            ushort4 v[8];
#pragma unroll
            for (int u = 0; u < 8; ++u) {
                v[u] = *(const ushort4*)(srcb + (size_t)n[u] * CH + (size_t)c0);
            }
#pragma unroll
            for (int u = 0; u < 8; u += 2) {
                a0 += w[u] * b2f(v[u].x);
                a1 += w[u] * b2f(v[u].y);
                a2 += w[u] * b2f(v[u].z);
                a3 += w[u] * b2f(v[u].w);
                d0 += w[u + 1] * b2f(v[u + 1].x);
                d1 += w[u + 1] * b2f(v[u + 1].y);
                d2 += w[u + 1] * b2f(v[u + 1].z);
                d3 += w[u + 1] * b2f(v[u + 1].w);
            }
        }
        for (; e < e1; ++e) {
            int nb = ccol[e];
            if (nb < 0 || nb >= NNODE) continue;
            float wv = cnorm[e];
            ushort4 v = *(const ushort4*)(srcb + (size_t)nb * CH + (size_t)c0);
            a0 += wv * b2f(v.x); a1 += wv * b2f(v.y);
            a2 += wv * b2f(v.z); a3 += wv * b2f(v.w);
        }
    }
    ushort4 o;
    o.x = f2b(san(a0 + d0));
    o.y = f2b(san(a1 + d1));
    o.z = f2b(san(a2 + d2));
    o.w = f2b(san(a3 + d3));
    *(ushort4*)(P + (size_t)wid * CH + (size_t)c0) = o;
}

// fast GEMM (no aliasing): grid (rows/64, 2); 64 rows x 128 cols, K=512.
// A-tile staged once per kh, reused across 2 j-tiles (halves A traffic).
__global__ __launch_bounds__(256) void k_gemm2(const u16* srcb, const float* srcf,
                                               const u16* P, const u16* Wtl,
                                               const u16* gam, const u16* bet,
                                               u16* dst, int mode,
                                               const int* flag, int use_f32) {
    __shared__ u16 As[64 * LDSP];
    __shared__ u16 Bs[64 * LDSP];
    const int tid = (int)threadIdx.x;
    const int m0 = (int)blockIdx.x * 64;
    const int j0 = (int)blockIdx.y * 128;
    const int w = tid >> 6;
    const int lane = tid & 63;
    const int mL = lane & 15;
    const int q = lane >> 4;
    const int dt = (use_f32 != 0) ? flag[0] : 0;
    f32x4 z4 = {0.f, 0.f, 0.f, 0.f};
    f32x4 acc[2][4];
#pragma unroll
    for (int jt = 0; jt < 2; ++jt)
#pragma unroll
        for (int t = 0; t < 4; ++t) acc[jt][t] = z4;

    for (int kh = 0; kh < 4; ++kh) {
        __syncthreads();
#pragma unroll
        for (int it = 0; it < 4; ++it) {
            int idx = it * 256 + tid;
            int r = idx >> 4;
            int c8 = idx & 15;
            int gm = m0 + r;
            uint4 av = make_uint4(0u, 0u, 0u, 0u);
            if (gm < NNODE) {
                if (kh < 2) {
                    size_t off = (size_t)gm * CH + (size_t)(kh * 128 + c8 * 8);
                    if (dt != 0) {
                        const float4* fp = (const float4*)(srcf + off);
                        float4 v0 = fp[0];
                        float4 v1 = fp[1];
                        av.x = (u32)f2b(v0.x) | ((u32)f2b(v0.y) << 16);
                        av.y = (u32)f2b(v0.z) | ((u32)f2b(v0.w) << 16);
                        av.z = (u32)f2b(v1.x) | ((u32)f2b(v1.y) << 16);
                        av.w = (u32)f2b(v1.z) | ((u32)f2b(v1.w) << 16);
                    } else {
                        av = *(const uint4*)(srcb + off);
                    }
                } else {
                    av = *(const uint4*)(P + (size_t)gm * CH +
                                         (size_t)((kh - 2) * 128 + c8 * 8));
                }
            }
            *(uint4*)(&As[r * LDSP + c8 * 8]) = av;
        }
        for (int jt = 0; jt < 2; ++jt) {
            if (jt > 0) __syncthreads();
#pragma unroll
            for (int it = 0; it < 4; ++it) {
                int idx = it * 256 + tid;
                int r = idx >> 4;
                int c8 = idx & 15;
                uint4 bv = *(const uint4*)(Wtl + (size_t)(j0 + jt * 64 + r) * 512 +
                                           (size_t)(kh * 128 + c8 * 8));
                *(uint4*)(&Bs[r * LDSP + c8 * 8]) = bv;
            }
            __syncthreads();
#pragma unroll
            for (int kt = 0; kt < 4; ++kt) {
                int ko = kt * 32 + q * 8;
                short8 a = *(const short8*)(&As[(w * 16 + mL) * LDSP + ko]);
#pragma unroll
                for (int t = 0; t < 4; ++t) {
                    short8 b = *(const short8*)(&Bs[(t * 16 + mL) * LDSP + ko]);
                    acc[jt][t] = __builtin_amdgcn_mfma_f32_16x16x32_bf16(
                        a, b, acc[jt][t], 0, 0, 0);
                }
            }
        }
    }
#pragma unroll
    for (int jt = 0; jt < 2; ++jt) {
#pragma unroll
        for (int t = 0; t < 4; ++t) {
            int j = j0 + jt * 64 + t * 16 + mL;
            float s = b2f(gam[j]) * RS_BN;
            float bb = b2f(bet[j]);
#pragma unroll
            for (int rr = 0; rr < 4; ++rr) {
                int gm = m0 + w * 16 + q * 4 + rr;
                if (gm < NNODE) {
                    float v = acc[jt][t][rr];
                    v = (mode == 0) ? fmaxf(v * s + bb, 0.f)
                                    : fmaxf(v, 0.f) * s + bb;
                    dst[(size_t)gm * CH + (size_t)j] = f2b(san(v));
                }
            }
        }
    }
}

// aliased fallback GEMM (block owns full rows; dst may alias src/P)
__global__ __launch_bounds__(256) void k_gemma(const u16* srcb, const float* srcf,
                                               const u16* P, const u16* Wtl,
                                               const u16* gam, const u16* bet,
                                               u16* dst, int mode,
                                               const int* flag, int use_f32) {
    __shared__ u16 As[64 * LDSP];
    __shared__ u16 Bs[64 * LDSP];
    const int tid = (int)threadIdx.x;
    const int m0 = (int)blockIdx.x * 64;
    const int w = tid >> 6;
    const int lane = tid & 63;
    const int mL = lane & 15;
    const int q = lane >> 4;
    const int dt = (use_f32 != 0) ? flag[0] : 0;
    f32x4 z4 = {0.f, 0.f, 0.f, 0.f};
    f32x4 acc[4][4];
#pragma unroll
    for (int jt = 0; jt < 4; ++jt)
#pragma unroll
        for (int t = 0; t < 4; ++t) acc[jt][t] = z4;

    for (int kh = 0; kh < 4; ++kh) {
        __syncthreads();
#pragma unroll
        for (int it = 0; it < 4; ++it) {
            int idx = it * 256 + tid;
            int r = idx >> 4;
            int c8 = idx & 15;
            int gm = m0 + r;
            uint4 av = make_uint4(0u, 0u, 0u, 0u);
            if (gm < NNODE) {
                if (kh < 2) {
                    size_t off = (size_t)gm * CH + (size_t)(kh * 128 + c8 * 8);
                    if (dt != 0) {
                        const float4* fp = (const float4*)(srcf + off);
                        float4 v0 = fp[0];
                        float4 v1 = fp[1];
                        av.x = (u32)f2b(v0.x) | ((u32)f2b(v0.y) << 16);
                        av.y = (u32)f2b(v0.z) | ((u32)f2b(v0.w) << 16);
                        av.z = (u32)f2b(v1.x) | ((u32)f2b(v1.y) << 16);
                        av.w = (u32)f2b(v1.z) | ((u32)f2b(v1.w) << 16);
                    } else {
                        av = *(const uint4*)(srcb + off);
                    }
                } else {
                    av = *(const uint4*)(P + (size_t)gm * CH +
                                         (size_t)((kh - 2) * 128 + c8 * 8));
                }
            }
            *(uint4*)(&As[r * LDSP + c8 * 8]) = av;
        }
        for (int jt = 0; jt < 4; ++jt) {
            if (jt > 0) __syncthreads();
#pragma unroll
            for (int it = 0; it < 4; ++it) {
                int idx = it * 256 + tid;
                int r = idx >> 4;
                int c8 = idx & 15;
                uint4 bv = *(const uint4*)(Wtl + (size_t)(jt * 64 + r) * 512 +
                                           (size_t)(kh * 128 + c8 * 8));
                *(uint4*)(&Bs[r * LDSP + c8 * 8]) = bv;
            }
            __syncthreads();
#pragma unroll
            for (int kt = 0; kt < 4; ++kt) {
                int ko = kt * 32 + q * 8;
                short8 a = *(const short8*)(&As[(w * 16 + mL) * LDSP + ko]);
#pragma unroll
                for (int t = 0; t < 4; ++t) {
                    short8 b = *(const short8*)(&Bs[(t * 16 + mL) * LDSP + ko]);
                    acc[jt][t] = __builtin_amdgcn_mfma_f32_16x16x32_bf16(
                        a, b, acc[jt][t], 0, 0, 0);
                }
            }
        }
    }
#pragma unroll
    for (int jt = 0; jt < 4; ++jt) {
#pragma unroll
        for (int t = 0; t < 4; ++t) {
            int j = jt * 64 + t * 16 + mL;
            float s = b2f(gam[j]) * RS_BN;
            float bb = b2f(bet[j]);
#pragma unroll
            for (int rr = 0; rr < 4; ++rr) {
                int gm = m0 + w * 16 + q * 4 + rr;
                if (gm < NNODE) {
                    float v = acc[jt][t][rr];
                    v = (mode == 0) ? fmaxf(v * s + bb, 0.f)
                                    : fmaxf(v, 0.f) * s + bb;
                    dst[(size_t)gm * CH + (size_t)j] = f2b(san(v));
                }
            }
        }
    }
}

// pool: 8 chunks/graph, atomic accumulate into zagg (zeroed per launch)
__global__ __launch_bounds__(256) void k_pool(const u16* h, float* zagg, int l) {
    int b = (int)blockIdx.x;
    int g = b >> 3;
    int chk = b & 7;
    int c = (int)threadIdx.x;
    const u16* p = h + ((size_t)g * NODES_PER_G + (size_t)(chk * 50)) * CH +
                   (size_t)c;
    float s = 0.f;
#pragma unroll 5
    for (int n = 0; n < 50; ++n) s += b2f(p[(size_t)n * CH]);
    atomicAdd(&zagg[g * JKW + l * CH + c], s * (1.0f / (float)NODES_PER_G));
}

// write z_agg output region from zagg
__global__ __launch_bounds__(256) void k_zout(const float* zagg, u16* outb,
                                              float* outf, const int* flag) {
    int i = (int)(blockIdx.x * 256u + threadIdx.x);
    if (i >= NG * JKW) return;
    float v = san(zagg[i]);
    if (flag[0] != 0) {
        outf[i] = v;
    } else {
        outb[i] = f2b(v);
    }
}

__global__ __launch_bounds__(256) void k_head(const float* zagg, const u16* w1,
                                              const u16* b1, const u16* cg,
                                              const u16* cbe, const u16* w2,
                                              const u16* b2, u16* loutb,
                                              float* loutf, const int* flag) {
    __shared__ float zin[JKW];
    __shared__ float zz[256];
    __shared__ float red[256];
    int g = (int)blockIdx.x;
    int t = (int)threadIdx.x;
    for (int i = t; i < JKW; i += 256) zin[i] = zagg[g * JKW + i];
    __syncthreads();
    float acc = b2f(b1[t]);
    const u16* wr = w1 + (size_t)t * JKW;
    for (int k = 0; k < JKW; ++k) acc += zin[k] * b2f(wr[k]);
    float z = san(fmaxf(acc, 0.f) * (b2f(cg[t]) * RS_BN) + b2f(cbe[t]));
    zz[t] = z;
    __syncthreads();
    for (int cls = 0; cls < 2; ++cls) {
        red[t] = zz[t] * b2f(w2[cls * 256 + t]);
        __syncthreads();
        for (int s = 128; s > 0; s >>= 1) {
            if (t < s) red[t] += red[t + s];
            __syncthreads();
        }
        if (t == 0) {
            float val = san(red[0] + b2f(b2[cls]));
            if (flag[0] != 0) {
                loutf[g * 2 + cls] = val;
            } else {
                loutb[g * 2 + cls] = f2b(val);
            }
        }
        __syncthreads();
    }
}

extern "C" void kernel_launch(void* const* d_in, const int* in_sizes, int n_in,
                              void* d_out, int out_size, void* d_ws, size_t ws_size,
                              hipStream_t stream) {
    (void)in_sizes; (void)n_in; (void)out_size;
    const u16*   xb  = (const u16*)d_in[0];
    const float* xf  = (const float*)d_in[0];
    u16*         xs  = (u16*)d_in[0];   // scratch h-buffer; harness restores d_in
    const int*   ei  = (const int*)d_in[1];
    const u16*   cwb = (const u16*)d_in[3];
    const float* cwf = (const float*)d_in[3];
    u16*   outb = (u16*)d_out;
    float* outf = (float*)d_out;

    char* p = (char*)d_ws;
    size_t used = 0;
    auto alloc = [&](size_t bytes) {
        char* r = p;
        size_t a = (bytes + 255) & ~(size_t)255;
        p += a;
        used += a;
        return r;
    };
    int*   deg    = (int*)alloc((size_t)NNODE * 4);
    int*   offs   = (int*)alloc((size_t)(NNODE + 1) * 4);
    int*   cursor = (int*)alloc((size_t)NNODE * 4);
    float* dis    = (float*)alloc((size_t)NNODE * 4);
    int*   ccol   = (int*)alloc((size_t)NEDGE * 4);
    float* cnorm  = (float*)alloc((size_t)NEDGE * 4);
    int*   bsum   = (int*)alloc((size_t)NBLK_SCAN * 4);
    int*   boff   = (int*)alloc((size_t)NBLK_SCAN * 4);
    u16*   Wtl    = (u16*)alloc((size_t)256 * 512 * 2);
    u16*   P0     = (u16*)alloc((size_t)NNODE * CH * 2);
    float* zagg   = (float*)alloc((size_t)NG * JKW * 4);
    int*   flag   = (int*)alloc(256);
    u16*   pbuf   = (u16*)alloc((size_t)199680 * 2);
    u16*   hA     = (u16*)alloc((size_t)NNODE * CH * 2);  // fast path only
    int fast = (used <= ws_size) ? 1 : 0;

    u16* c_bng = pbuf + 0;
    u16* c_bnb = pbuf + 768;
    u16* c_b1  = pbuf + 1536;
    u16* c_cg  = pbuf + 1792;
    u16* c_cbe = pbuf + 2048;
    u16* c_w2  = pbuf + 2304;
    u16* c_b2  = pbuf + 2816;
    u16* c_w1  = pbuf + 3072;

    k_detect<<<1, 64, 0, stream>>>(xb, flag);
    k_cvt_all<<<780, 256, 0, stream>>>(
        (const u16*)d_in[4], (const float*)d_in[4],
        (const u16*)d_in[5], (const float*)d_in[5],
        (const u16*)d_in[6], (const float*)d_in[6],
        (const u16*)d_in[7], (const float*)d_in[7],
        (const u16*)d_in[8], (const float*)d_in[8],
        (const u16*)d_in[9], (const float*)d_in[9],
        (const u16*)d_in[10], (const float*)d_in[10],
        (const u16*)d_in[11], (const float*)d_in[11],
        pbuf, flag);

    k_zero<<<(NNODE + 255) / 256, 256, 0, stream>>>(deg);
    k_zeroz<<<(NG * JKW + 255) / 256, 256, 0, stream>>>(zagg);
    k_deg<<<(NEDGE + 255) / 256, 256, 0, stream>>>(ei, deg);
    k_bsum<<<NBLK_SCAN, 256, 0, stream>>>(deg, bsum);
    k_bscan<<<1, 128, 0, stream>>>(bsum, boff, offs);
    k_scat<<<NBLK_SCAN, 256, 0, stream>>>(deg, boff, offs, cursor, dis);
    k_fill<<<(NEDGE + 255) / 256, 256, 0, stream>>>(ei, dis, cursor, ccol, cnorm);

    const int gblk = (NNODE + 63) / 64;
    dim3 g2(gblk, 2, 1);
    for (int l = 0; l < 3; ++l) {
        int uf = (l == 0) ? 1 : 0;
        int mode = (l == 0) ? 0 : 1;
        k_wt<<<256, 256, 0, stream>>>(cwb, cwf, Wtl, l, flag);
        if (fast != 0) {
            const u16* sb;
            u16* hd;
            if (l == 0)      { sb = xb; hd = hA; }
            else if (l == 1) { sb = hA; hd = xs; }
            else             { sb = xs; hd = hA; }
            k_propP<<<NNODE / 4, 256, 0, stream>>>(sb, xf, offs, ccol, cnorm,
                                                   P0, flag, uf);
            k_gemm2<<<g2, 256, 0, stream>>>(sb, xf, P0, Wtl, c_bng + l * 256,
                                            c_bnb + l * 256, hd, mode, flag, uf);
            k_pool<<<NG * 8, 256, 0, stream>>>(hd, zagg, l);
        } else {
            const u16* sb;
            u16* hp;
            if (l == 0)      { sb = xb; hp = P0; }
            else if (l == 1) { sb = P0; hp = xs; }
            else             { sb = xs; hp = P0; }
            k_propP<<<NNODE / 4, 256, 0, stream>>>(sb, xf, offs, ccol, cnorm,
                                                   hp, flag, uf);
            k_gemma<<<gblk, 256, 0, stream>>>(sb, xf, hp, Wtl, c_bng + l * 256,
                                              c_bnb + l * 256, hp, mode, flag, uf);
            k_pool<<<NG * 8, 256, 0, stream>>>(hp, zagg, l);
        }
    }
    k_zout<<<(NG * JKW + 255) / 256, 256, 0, stream>>>(zagg, outb, outf, flag);
    k_head<<<NG, 256, 0, stream>>>(zagg, c_w1, c_b1, c_cg, c_cbe, c_w2, c_b2,
                                   outb + NG * JKW, outf + NG * JKW, flag);
}